// Round 23
// baseline (285.924 us; speedup 1.0000x reference)
//
#include <hip/hip_runtime.h>
#include <hip/hip_bf16.h>
#include <cstdint>

using f32x4   = __attribute__((ext_vector_type(4))) float;
using f32x16  = __attribute__((ext_vector_type(16))) float;
using bf16x8  = __attribute__((ext_vector_type(8))) short;

__device__ inline ushort f2bf(float f) {
    union { float f; uint u; } x; x.f = f;
    uint u = x.u;
    return (ushort)((u + 0x7FFFu + ((u >> 16) & 1u)) >> 16);
}

__device__ inline float bf2f(ushort v) {
    union { uint u; float f; } x; x.u = (uint)v << 16;
    return x.f;
}

// async global->LDS, 16B per lane; lds base must be wave-uniform
__device__ inline void gload16(const ushort* g, ushort* lds) {
    __builtin_amdgcn_global_load_lds(
        (const __attribute__((address_space(1))) unsigned int*)g,
        (__attribute__((address_space(3))) unsigned int*)lds, 16, 0, 0);
}

// ---------------- prep: 4 weight transposes + LN1, one launch ----------------
__device__ inline void transpose_body(const float* __restrict__ w,
                                      ushort* __restrict__ wt,
                                      int K, int N, int bx, int by,
                                      float (*tile)[33]) {
    const int bn = bx * 32, bk = by * 32;
    const int tx = threadIdx.x & 31, ty = threadIdx.x >> 5;
#pragma unroll
    for (int i = 0; i < 32; i += 8)
        tile[ty + i][tx] = w[(size_t)(bk + ty + i) * N + bn + tx];
    __syncthreads();
#pragma unroll
    for (int i = 0; i < 32; i += 8)
        wt[(size_t)(bn + ty + i) * K + bk + tx] = f2bf(tile[tx][ty + i]);
}

__device__ inline void ln_body(const float* __restrict__ x,
                               const float* __restrict__ g,
                               const float* __restrict__ b,
                               ushort* __restrict__ out, int row,
                               float* sa, float* sb) {
    const float* xr = x + (size_t)row * 768;
    const int t = threadIdx.x;
    float v0 = xr[t], v1 = xr[t + 256], v2 = xr[t + 512];
    float s  = v0 + v1 + v2;
    float sq = v0 * v0 + v1 * v1 + v2 * v2;
#pragma unroll
    for (int off = 32; off > 0; off >>= 1) {
        s  += __shfl_down(s, off);
        sq += __shfl_down(sq, off);
    }
    const int wv = t >> 6, lane = t & 63;
    if (lane == 0) { sa[wv] = s; sb[wv] = sq; }
    __syncthreads();
    s  = sa[0] + sa[1] + sa[2] + sa[3];
    sq = sb[0] + sb[1] + sb[2] + sb[3];
    const float mu   = s * (1.0f / 768.0f);
    const float var  = sq * (1.0f / 768.0f) - mu * mu;
    const float rstd = rsqrtf(var + 1e-5f);
    ushort* orow = out + (size_t)row * 768;
    orow[t]       = f2bf((v0 - mu) * rstd * g[t]       + b[t]);
    orow[t + 256] = f2bf((v1 - mu) * rstd * g[t + 256] + b[t + 256]);
    orow[t + 512] = f2bf((v2 - mu) * rstd * g[t + 512] + b[t + 512]);
}

__global__ __launch_bounds__(256) void prep(const float* __restrict__ qkv_w,
                                            const float* __restrict__ proj_w,
                                            const float* __restrict__ fc1_w,
                                            const float* __restrict__ fc2_w,
                                            ushort* __restrict__ qkv_wt,
                                            ushort* __restrict__ proj_wt,
                                            ushort* __restrict__ fc1_wt,
                                            ushort* __restrict__ fc2_wt,
                                            const float* __restrict__ x,
                                            const float* __restrict__ ln1_g,
                                            const float* __restrict__ ln1_b,
                                            ushort* __restrict__ hb) {
    __shared__ float tile[32][33];
    __shared__ float sa[4], sb[4];
    int blk = blockIdx.x;
    if (blk < 1728)      transpose_body(qkv_w, qkv_wt, 768, 2304, blk % 72, blk / 72, tile);
    else if (blk < 2304) { blk -= 1728; transpose_body(proj_w, proj_wt, 768, 768,  blk % 24, blk / 24, tile); }
    else if (blk < 4608) { blk -= 2304; transpose_body(fc1_w,  fc1_wt,  768, 3072, blk % 96, blk / 96, tile); }
    else if (blk < 6912) { blk -= 4608; transpose_body(fc2_w,  fc2_wt,  3072, 768, blk % 24, blk / 24, tile); }
    else                 ln_body(x, ln1_g, ln1_b, hb, blk - 6912, sa, sb);
}

// ---------------- LayerNorm, bf16 input variant (for ln2 over bf16 x1) --------
__global__ __launch_bounds__(256) void ln_bf16_bin(const ushort* __restrict__ x,
                                                   const float* __restrict__ g,
                                                   const float* __restrict__ b,
                                                   ushort* __restrict__ out) {
    __shared__ float sa[4], sb[4];
    const int row = blockIdx.x;
    const ushort* xr = x + (size_t)row * 768;
    const int t = threadIdx.x;
    float v0 = bf2f(xr[t]), v1 = bf2f(xr[t + 256]), v2 = bf2f(xr[t + 512]);
    float s  = v0 + v1 + v2;
    float sq = v0 * v0 + v1 * v1 + v2 * v2;
#pragma unroll
    for (int off = 32; off > 0; off >>= 1) {
        s  += __shfl_down(s, off);
        sq += __shfl_down(sq, off);
    }
    const int wv = t >> 6, lane = t & 63;
    if (lane == 0) { sa[wv] = s; sb[wv] = sq; }
    __syncthreads();
    s  = sa[0] + sa[1] + sa[2] + sa[3];
    sq = sb[0] + sb[1] + sb[2] + sb[3];
    const float mu   = s * (1.0f / 768.0f);
    const float var  = sq * (1.0f / 768.0f) - mu * mu;
    const float rstd = rsqrtf(var + 1e-5f);
    ushort* orow = out + (size_t)row * 768;
    orow[t]       = f2bf((v0 - mu) * rstd * g[t]       + b[t]);
    orow[t + 256] = f2bf((v1 - mu) * rstd * g[t + 256] + b[t + 256]);
    orow[t + 512] = f2bf((v2 - mu) * rstd * g[t + 512] + b[t + 512]);
}

// ---- bf16 MFMA GEMM: BK=32, 3-buffer 2-deep prefetch + LDS XOR swizzle -------
// NEW (R23): the fragment reads were 8-way bank-conflicted (16 lanes read 16
// rows at 64B stride, same 16B column -> 2 bank groups). Fix per rule #21:
// LDS dest stays linear (global_load_lds requirement); the GLOBAL source quad
// is permuted per row (quad' = quad ^ (row&3)), so LDS[row][u] = A[row][u^(row&3)];
// fragment reads apply the same XOR (u = lr ^ (lc&3)). Spread 2 -> 4 slots:
// conflicts 8-way -> 4-way (2.94x -> 1.58x per m136). Coalescing preserved
// (permutation stays within each 64B global line). Values identical.
// EPI: 0 = bias -> bf16; 2 = bias + gelu -> bf16
// EPI: 3 = qkv mode: cols < 768 (Q) -> bf16 * 1/8; 768..1535 (K) -> bf16;
//          >= 1536 (V) -> transposed store into out2 as vT[(b*12+h)*64+d][key]
// EPI: 4 = bias + f32 residual -> bf16 out (proj)
// EPI: 5 = bias + bf16 residual -> f32 out (fc2)
// SWZ: 1 = row-grouping XCD swizzle; requires (M/128) % 8 == 0.
template <int EPI, int SWZ>
__global__ __launch_bounds__(256) void gemm_bt(const ushort* __restrict__ A,
                                               const ushort* __restrict__ Bt,
                                               const float* __restrict__ bias,
                                               const void* __restrict__ resid,
                                               void* __restrict__ out,
                                               void* __restrict__ out2,
                                               int M, int N, int K, int gx) {
    __shared__ ushort As[3][128 * 32];
    __shared__ ushort Bs[3][128 * 32];
    int bm, bn;
    if (SWZ) {
        const int bid = blockIdx.x;
        const int x = bid & 7, s = bid >> 3;
        bm = ((s / gx) * 8 + x) * 128;
        bn = (s % gx) * 128;
    } else {
        bm = blockIdx.y * 128;
        bn = blockIdx.x * 128;
    }
    const int t    = threadIdx.x;
    const int lane = t & 63;
    const int w    = t >> 6;
    const int wr   = w >> 1, wc = w & 1;
    const int lr   = lane >> 4, lc = lane & 15;

    const f32x4 fzero = {0.f, 0.f, 0.f, 0.f};
    f32x4 acc[4][4];
#pragma unroll
    for (int ai = 0; ai < 4; ++ai)
#pragma unroll
        for (int bj = 0; bj < 4; ++bj) acc[ai][bj] = fzero;

    // staging with source-side quad swizzle: lane covers row srow, global quad
    // (lane&3)^(srow&3); LDS write is linear (HW: base + lane*16B)
    const int srow  = lane >> 2;
    const int squad = (lane & 3) ^ (srow & 3);
    const int sk8   = squad * 8;
    const ushort* Ag0 = A  + (size_t)(bm + w * 16 + srow) * K + sk8;
    const ushort* Ag1 = Ag0 + (size_t)64 * K;
    const ushort* Bg0 = Bt + (size_t)(bn + w * 16 + srow) * K + sk8;
    const ushort* Bg1 = Bg0 + (size_t)64 * K;
    const int lo0 = (w * 16) * 32, lo1 = (64 + w * 16) * 32;

    const int nt = K >> 5;
    auto issue = [&](int tile, int buf) {
        const int kb = tile << 5;
        gload16(Ag0 + kb, &As[buf][lo0]);
        gload16(Ag1 + kb, &As[buf][lo1]);
        gload16(Bg0 + kb, &Bs[buf][lo0]);
        gload16(Bg1 + kb, &Bs[buf][lo1]);
    };
    issue(0, 0);
    if (nt > 1) issue(1, 1);

    // fragment read offset: row&3 == lc&3 (tile rows are multiples of 4 + lc)
    const int rq = (lr ^ (lc & 3)) * 8;

    for (int tk = 0; tk < nt; ++tk) {
        if (tk + 1 < nt) asm volatile("s_waitcnt vmcnt(4)" ::: "memory");
        else             asm volatile("s_waitcnt vmcnt(0)" ::: "memory");
        __builtin_amdgcn_sched_barrier(0);
        __builtin_amdgcn_s_barrier();
        __builtin_amdgcn_sched_barrier(0);
        if (tk + 2 < nt) issue(tk + 2, (tk + 2) % 3);
        const int cb = tk % 3;
        bf16x8 af[4], bf[4];
#pragma unroll
        for (int ai = 0; ai < 4; ++ai)
            af[ai] = *(const bf16x8*)&As[cb][(wr * 64 + ai * 16 + lc) * 32 + rq];
#pragma unroll
        for (int bj = 0; bj < 4; ++bj)
            bf[bj] = *(const bf16x8*)&Bs[cb][(wc * 64 + bj * 16 + lc) * 32 + rq];
#pragma unroll
        for (int ai = 0; ai < 4; ++ai)
#pragma unroll
            for (int bj = 0; bj < 4; ++bj)
                acc[ai][bj] = __builtin_amdgcn_mfma_f32_16x16x32_bf16(af[ai], bf[bj],
                                                                      acc[ai][bj], 0, 0, 0);
    }

#pragma unroll
    for (int ai = 0; ai < 4; ++ai) {
#pragma unroll
        for (int bj = 0; bj < 4; ++bj) {
            int col  = bn + wc * 64 + bj * 16 + lc;
            float bs = bias[col];
            if (EPI == 3 && col >= 1536) {
                int row0 = bm + wr * 64 + ai * 16 + lr * 4;
                int bb   = row0 >> 10, key0 = row0 & 1023;
                int c    = col - 1536;
                int h    = c >> 6, d = c & 63;
                ushort4 pk;
                pk.x = f2bf(acc[ai][bj][0] + bs);
                pk.y = f2bf(acc[ai][bj][1] + bs);
                pk.z = f2bf(acc[ai][bj][2] + bs);
                pk.w = f2bf(acc[ai][bj][3] + bs);
                *(ushort4*)((ushort*)out2 +
                            ((size_t)(bb * 12 + h) * 64 + d) * 1024 + key0) = pk;
                continue;
            }
            const float qsc = (EPI == 3 && col < 768) ? 0.125f : 1.0f;
#pragma unroll
            for (int j = 0; j < 4; ++j) {
                int row   = bm + wr * 64 + ai * 16 + lr * 4 + j;
                size_t idx = (size_t)row * N + col;
                float val = acc[ai][bj][j] + bs;
                if (EPI == 4) {
                    val += ((const float*)resid)[idx];
                    ((ushort*)out)[idx] = f2bf(val);
                } else if (EPI == 5) {
                    val += bf2f(((const ushort*)resid)[idx]);
                    ((float*)out)[idx] = val;
                } else if (EPI == 2) {
                    val = 0.5f * val * (1.0f + erff(val * 0.70710678118f));
                    ((ushort*)out)[idx] = f2bf(val);
                } else {
                    ((ushort*)out)[idx] = f2bf(val * qsc);
                }
            }
        }
    }
}

// ------- attention: 32x32x16 MFMA, swapped QK^T, max-free softmax -------------
// qkv: bf16 [8192, 2304] (Q cols 0..767 pre-scaled by 1/8, K cols 768..1535)
// vT : bf16 [96][64][1024]   out: bf16 [8192, 768]
__global__ __launch_bounds__(256) void attn_mfma(const ushort* __restrict__ qkv,
                                                 const ushort* __restrict__ vT,
                                                 ushort* __restrict__ outb) {
    __shared__ ushort Kls[64 * 72];
    __shared__ ushort Vtls[64 * 72];

    const int bid = blockIdx.x;
    const int b   = bid / 96;
    const int rem = bid % 96;
    const int h   = rem >> 3;
    const int qc  = rem & 7;
    const int t    = threadIdx.x;
    const int w    = t >> 6;
    const int lane = t & 63;
    const int l31  = lane & 31;
    const int hi   = lane >> 5;
    const int q0   = qc * 128 + w * 32;
    const size_t bbase = (size_t)b * 1024;
    const ushort* vTh = vT + ((size_t)(b * 12 + h) * 64) * 1024;

    bf16x8 qb[4];
    {
        const size_t qrow = (bbase + q0 + l31) * 2304 + h * 64;
#pragma unroll
        for (int dblk = 0; dblk < 4; ++dblk)
            qb[dblk] = *(const bf16x8*)(qkv + qrow + dblk * 16 + hi * 8);
    }

    f32x16 O[2];
#pragma unroll
    for (int ob = 0; ob < 2; ++ob)
#pragma unroll
        for (int r = 0; r < 16; ++r) O[ob][r] = 0.0f;
    float l = 0.0f;

    for (int kt = 0; kt < 16; ++kt) {
        const int k0 = kt * 64;
        __syncthreads();
#pragma unroll
        for (int i = 0; i < 2; ++i) {
            int idx = t + i * 256;
            int key = idx >> 3, seg = idx & 7;
            uint4 u = *(const uint4*)(qkv + (bbase + k0 + key) * 2304 + 768 +
                                      h * 64 + seg * 8);
            *(uint4*)&Kls[key * 72 + seg * 8] = u;
        }
#pragma unroll
        for (int i = 0; i < 2; ++i) {
            int idx = t + i * 256;
            int d = idx >> 3, seg = idx & 7;
            uint4 u = *(const uint4*)(vTh + (size_t)d * 1024 + k0 + seg * 8);
            *(uint4*)&Vtls[d * 72 + seg * 8] = u;
        }
        __syncthreads();

        f32x16 s[2];
#pragma unroll
        for (int kb = 0; kb < 2; ++kb) {
            f32x16 acc;
#pragma unroll
            for (int r = 0; r < 16; ++r) acc[r] = 0.0f;
#pragma unroll
            for (int dblk = 0; dblk < 4; ++dblk) {
                bf16x8 ka = *(const bf16x8*)&Kls[(kb * 32 + l31) * 72 + dblk * 16 + hi * 8];
                acc = __builtin_amdgcn_mfma_f32_32x32x16_bf16(ka, qb[dblk], acc, 0, 0, 0);
            }
            s[kb] = acc;
        }

        float psum = 0.0f;
#pragma unroll
        for (int kb = 0; kb < 2; ++kb)
#pragma unroll
            for (int r = 0; r < 16; ++r) {
                float p = __expf(s[kb][r]);
                s[kb][r] = p;
                psum += p;
            }
        psum += __shfl_xor(psum, 32);
        l += psum;

        bf16x8 pb[4];
#pragma unroll
        for (int kb16 = 0; kb16 < 4; ++kb16) {
            const int sb = kb16 >> 1, r0 = (kb16 & 1) * 8;
            uint own01 = (uint)f2bf(s[sb][r0 + 0]) | ((uint)f2bf(s[sb][r0 + 1]) << 16);
            uint own23 = (uint)f2bf(s[sb][r0 + 2]) | ((uint)f2bf(s[sb][r0 + 3]) << 16);
            uint own45 = (uint)f2bf(s[sb][r0 + 4]) | ((uint)f2bf(s[sb][r0 + 5]) << 16);
            uint own67 = (uint)f2bf(s[sb][r0 + 6]) | ((uint)f2bf(s[sb][r0 + 7]) << 16);
            uint sw01 = __shfl_xor(own01, 32);
            uint sw23 = __shfl_xor(own23, 32);
            uint sw45 = __shfl_xor(own45, 32);
            uint sw67 = __shfl_xor(own67, 32);
            uint d0 = hi ? sw45 : own01;
            uint d1 = hi ? sw67 : own23;
            uint d2 = hi ? own45 : sw01;
            uint d3 = hi ? own67 : sw23;
            union { uint u[4]; bf16x8 v; } cvt;
            cvt.u[0] = d0; cvt.u[1] = d1; cvt.u[2] = d2; cvt.u[3] = d3;
            pb[kb16] = cvt.v;
        }

#pragma unroll
        for (int ob = 0; ob < 2; ++ob)
#pragma unroll
            for (int kb16 = 0; kb16 < 4; ++kb16) {
                bf16x8 va = *(const bf16x8*)&Vtls[(ob * 32 + l31) * 72 + kb16 * 16 + hi * 8];
                O[ob] = __builtin_amdgcn_mfma_f32_32x32x16_bf16(va, pb[kb16], O[ob], 0, 0, 0);
            }
    }

    const float inv = 1.0f / l;
    ushort* orow = outb + (bbase + q0 + l31) * 768 + h * 64;
#pragma unroll
    for (int ob = 0; ob < 2; ++ob)
#pragma unroll
        for (int qd = 0; qd < 4; ++qd) {
            ushort4 pk;
            pk.x = f2bf(O[ob][qd * 4 + 0] * inv);
            pk.y = f2bf(O[ob][qd * 4 + 1] * inv);
            pk.z = f2bf(O[ob][qd * 4 + 2] * inv);
            pk.w = f2bf(O[ob][qd * 4 + 3] * inv);
            *(ushort4*)(orow + ob * 32 + qd * 8 + hi * 4) = pk;
        }
}

// ---------------- launch ----------------
extern "C" void kernel_launch(void* const* d_in, const int* in_sizes, int n_in,
                              void* d_out, int out_size, void* d_ws, size_t ws_size,
                              hipStream_t stream) {
    const float* x      = (const float*)d_in[0];
    const float* ln1_g  = (const float*)d_in[1];
    const float* ln1_b  = (const float*)d_in[2];
    const float* qkv_w  = (const float*)d_in[3];
    const float* qkv_b  = (const float*)d_in[4];
    const float* proj_w = (const float*)d_in[5];
    const float* proj_b = (const float*)d_in[6];
    const float* ln2_g  = (const float*)d_in[7];
    const float* ln2_b  = (const float*)d_in[8];
    const float* fc1_w  = (const float*)d_in[9];
    const float* fc1_b  = (const float*)d_in[10];
    const float* fc2_w  = (const float*)d_in[11];
    const float* fc2_b  = (const float*)d_in[12];

    char* ws = (char*)d_ws;
    auto alloc = [&](size_t bytes) {
        char* p = ws;
        ws += (bytes + 255) & ~(size_t)255;
        return p;
    };
    ushort* qkv_wt  = (ushort*)alloc((size_t)768 * 2304 * 2);
    ushort* proj_wt = (ushort*)alloc((size_t)768 * 768 * 2);
    ushort* fc1_wt  = (ushort*)alloc((size_t)768 * 3072 * 2);
    ushort* fc2_wt  = (ushort*)alloc((size_t)3072 * 768 * 2);
    ushort* hb      = (ushort*)alloc((size_t)8192 * 768 * 2);
    ushort* qkvb    = (ushort*)alloc((size_t)8192 * 2304 * 2);
    ushort* vTb     = (ushort*)alloc((size_t)96 * 64 * 1024 * 2);
    ushort* ob      = (ushort*)alloc((size_t)8192 * 768 * 2);
    ushort* x1b     = (ushort*)alloc((size_t)8192 * 768 * 2);   // bf16 residual stream
    ushort* h2b     = (ushort*)alloc((size_t)8192 * 768 * 2);
    ushort* h3b     = (ushort*)alloc((size_t)8192 * 3072 * 2);

    // fused: 4 weight transposes + LN1 in one launch
    prep<<<15104, 256, 0, stream>>>(qkv_w, proj_w, fc1_w, fc2_w,
                                    qkv_wt, proj_wt, fc1_wt, fc2_wt,
                                    x, ln1_g, ln1_b, hb);
    gemm_bt<3, 1><<<18 * 64, 256, 0, stream>>>(
        hb, qkv_wt, qkv_b, nullptr, qkvb, vTb, 8192, 2304, 768, 18);
    attn_mfma<<<768, 256, 0, stream>>>(qkvb, vTb, ob);
    gemm_bt<4, 1><<<6 * 64, 256, 0, stream>>>(
        ob, proj_wt, proj_b, x, x1b, nullptr, 8192, 768, 768, 6);
    ln_bf16_bin<<<8192, 256, 0, stream>>>(x1b, ln2_g, ln2_b, h2b);
    gemm_bt<2, 1><<<24 * 64, 256, 0, stream>>>(
        h2b, fc1_wt, fc1_b, nullptr, h3b, nullptr, 8192, 3072, 768, 24);
    gemm_bt<5, 1><<<6 * 64, 256, 0, stream>>>(
        h3b, fc2_wt, fc2_b, x1b, (float*)d_out, nullptr, 8192, 768, 3072, 6);
}

// Round 24
// 285.825 us; speedup vs baseline: 1.0003x; 1.0003x over previous
//
#include <hip/hip_runtime.h>
#include <hip/hip_bf16.h>
#include <cstdint>

using f32x4   = __attribute__((ext_vector_type(4))) float;
using f32x16  = __attribute__((ext_vector_type(16))) float;
using bf16x8  = __attribute__((ext_vector_type(8))) short;

__device__ inline ushort f2bf(float f) {
    union { float f; uint u; } x; x.f = f;
    uint u = x.u;
    return (ushort)((u + 0x7FFFu + ((u >> 16) & 1u)) >> 16);
}

__device__ inline float bf2f(ushort v) {
    union { uint u; float f; } x; x.u = (uint)v << 16;
    return x.f;
}

// async global->LDS, 16B per lane; lds base must be wave-uniform
__device__ inline void gload16(const ushort* g, ushort* lds) {
    __builtin_amdgcn_global_load_lds(
        (const __attribute__((address_space(1))) unsigned int*)g,
        (__attribute__((address_space(3))) unsigned int*)lds, 16, 0, 0);
}

// ---------------- prep: 4 weight transposes + LN1, one launch ----------------
__device__ inline void transpose_body(const float* __restrict__ w,
                                      ushort* __restrict__ wt,
                                      int K, int N, int bx, int by,
                                      float (*tile)[33]) {
    const int bn = bx * 32, bk = by * 32;
    const int tx = threadIdx.x & 31, ty = threadIdx.x >> 5;
#pragma unroll
    for (int i = 0; i < 32; i += 8)
        tile[ty + i][tx] = w[(size_t)(bk + ty + i) * N + bn + tx];
    __syncthreads();
#pragma unroll
    for (int i = 0; i < 32; i += 8)
        wt[(size_t)(bn + ty + i) * K + bk + tx] = f2bf(tile[tx][ty + i]);
}

__device__ inline void ln_body(const float* __restrict__ x,
                               const float* __restrict__ g,
                               const float* __restrict__ b,
                               ushort* __restrict__ out, int row,
                               float* sa, float* sb) {
    const float* xr = x + (size_t)row * 768;
    const int t = threadIdx.x;
    float v0 = xr[t], v1 = xr[t + 256], v2 = xr[t + 512];
    float s  = v0 + v1 + v2;
    float sq = v0 * v0 + v1 * v1 + v2 * v2;
#pragma unroll
    for (int off = 32; off > 0; off >>= 1) {
        s  += __shfl_down(s, off);
        sq += __shfl_down(sq, off);
    }
    const int wv = t >> 6, lane = t & 63;
    if (lane == 0) { sa[wv] = s; sb[wv] = sq; }
    __syncthreads();
    s  = sa[0] + sa[1] + sa[2] + sa[3];
    sq = sb[0] + sb[1] + sb[2] + sb[3];
    const float mu   = s * (1.0f / 768.0f);
    const float var  = sq * (1.0f / 768.0f) - mu * mu;
    const float rstd = rsqrtf(var + 1e-5f);
    ushort* orow = out + (size_t)row * 768;
    orow[t]       = f2bf((v0 - mu) * rstd * g[t]       + b[t]);
    orow[t + 256] = f2bf((v1 - mu) * rstd * g[t + 256] + b[t + 256]);
    orow[t + 512] = f2bf((v2 - mu) * rstd * g[t + 512] + b[t + 512]);
}

__global__ __launch_bounds__(256) void prep(const float* __restrict__ qkv_w,
                                            const float* __restrict__ proj_w,
                                            const float* __restrict__ fc1_w,
                                            const float* __restrict__ fc2_w,
                                            ushort* __restrict__ qkv_wt,
                                            ushort* __restrict__ proj_wt,
                                            ushort* __restrict__ fc1_wt,
                                            ushort* __restrict__ fc2_wt,
                                            const float* __restrict__ x,
                                            const float* __restrict__ ln1_g,
                                            const float* __restrict__ ln1_b,
                                            ushort* __restrict__ hb) {
    __shared__ float tile[32][33];
    __shared__ float sa[4], sb[4];
    int blk = blockIdx.x;
    if (blk < 1728)      transpose_body(qkv_w, qkv_wt, 768, 2304, blk % 72, blk / 72, tile);
    else if (blk < 2304) { blk -= 1728; transpose_body(proj_w, proj_wt, 768, 768,  blk % 24, blk / 24, tile); }
    else if (blk < 4608) { blk -= 2304; transpose_body(fc1_w,  fc1_wt,  768, 3072, blk % 96, blk / 96, tile); }
    else if (blk < 6912) { blk -= 4608; transpose_body(fc2_w,  fc2_wt,  3072, 768, blk % 24, blk / 24, tile); }
    else                 ln_body(x, ln1_g, ln1_b, hb, blk - 6912, sa, sb);
}

// ---------------- LayerNorm, bf16 input variant (for ln2 over bf16 x1) --------
__global__ __launch_bounds__(256) void ln_bf16_bin(const ushort* __restrict__ x,
                                                   const float* __restrict__ g,
                                                   const float* __restrict__ b,
                                                   ushort* __restrict__ out) {
    __shared__ float sa[4], sb[4];
    const int row = blockIdx.x;
    const ushort* xr = x + (size_t)row * 768;
    const int t = threadIdx.x;
    float v0 = bf2f(xr[t]), v1 = bf2f(xr[t + 256]), v2 = bf2f(xr[t + 512]);
    float s  = v0 + v1 + v2;
    float sq = v0 * v0 + v1 * v1 + v2 * v2;
#pragma unroll
    for (int off = 32; off > 0; off >>= 1) {
        s  += __shfl_down(s, off);
        sq += __shfl_down(sq, off);
    }
    const int wv = t >> 6, lane = t & 63;
    if (lane == 0) { sa[wv] = s; sb[wv] = sq; }
    __syncthreads();
    s  = sa[0] + sa[1] + sa[2] + sa[3];
    sq = sb[0] + sb[1] + sb[2] + sb[3];
    const float mu   = s * (1.0f / 768.0f);
    const float var  = sq * (1.0f / 768.0f) - mu * mu;
    const float rstd = rsqrtf(var + 1e-5f);
    ushort* orow = out + (size_t)row * 768;
    orow[t]       = f2bf((v0 - mu) * rstd * g[t]       + b[t]);
    orow[t + 256] = f2bf((v1 - mu) * rstd * g[t + 256] + b[t + 256]);
    orow[t + 512] = f2bf((v2 - mu) * rstd * g[t + 512] + b[t + 512]);
}

// ---- bf16 MFMA GEMM: BK=32, TRIPLE-buffered LDS, 2-deep prefetch (best) ------
// EPI: 0 = bias -> bf16; 2 = bias + gelu -> bf16
// EPI: 3 = qkv mode: cols < 768 (Q) -> bf16 * 1/8; 768..1535 (K) -> bf16;
//          >= 1536 (V) -> transposed store into out2 as vT[(b*12+h)*64+d][key]
// EPI: 4 = bias + f32 residual -> bf16 out (proj)
// EPI: 5 = bias + bf16 residual -> f32 out (fc2)
// SWZ: 1 = row-grouping XCD swizzle; requires (M/128) % 8 == 0.
template <int EPI, int SWZ>
__global__ __launch_bounds__(256) void gemm_bt(const ushort* __restrict__ A,
                                               const ushort* __restrict__ Bt,
                                               const float* __restrict__ bias,
                                               const void* __restrict__ resid,
                                               void* __restrict__ out,
                                               void* __restrict__ out2,
                                               int M, int N, int K, int gx) {
    __shared__ ushort As[3][128 * 32];
    __shared__ ushort Bs[3][128 * 32];
    int bm, bn;
    if (SWZ) {
        const int bid = blockIdx.x;
        const int x = bid & 7, s = bid >> 3;
        bm = ((s / gx) * 8 + x) * 128;
        bn = (s % gx) * 128;
    } else {
        bm = blockIdx.y * 128;
        bn = blockIdx.x * 128;
    }
    const int t    = threadIdx.x;
    const int lane = t & 63;
    const int w    = t >> 6;
    const int wr   = w >> 1, wc = w & 1;
    const int lr   = lane >> 4, lc = lane & 15;

    const f32x4 fzero = {0.f, 0.f, 0.f, 0.f};
    f32x4 acc[4][4];
#pragma unroll
    for (int ai = 0; ai < 4; ++ai)
#pragma unroll
        for (int bj = 0; bj < 4; ++bj) acc[ai][bj] = fzero;

    const int srow = lane >> 2;
    const int sk8  = (lane & 3) * 8;
    const ushort* Ag0 = A  + (size_t)(bm + w * 16 + srow) * K + sk8;
    const ushort* Ag1 = Ag0 + (size_t)64 * K;
    const ushort* Bg0 = Bt + (size_t)(bn + w * 16 + srow) * K + sk8;
    const ushort* Bg1 = Bg0 + (size_t)64 * K;
    const int lo0 = (w * 16) * 32, lo1 = (64 + w * 16) * 32;

    const int nt = K >> 5;
    auto issue = [&](int tile, int buf) {
        const int kb = tile << 5;
        gload16(Ag0 + kb, &As[buf][lo0]);
        gload16(Ag1 + kb, &As[buf][lo1]);
        gload16(Bg0 + kb, &Bs[buf][lo0]);
        gload16(Bg1 + kb, &Bs[buf][lo1]);
    };
    issue(0, 0);
    if (nt > 1) issue(1, 1);

    for (int tk = 0; tk < nt; ++tk) {
        if (tk + 1 < nt) asm volatile("s_waitcnt vmcnt(4)" ::: "memory");
        else             asm volatile("s_waitcnt vmcnt(0)" ::: "memory");
        __builtin_amdgcn_sched_barrier(0);
        __builtin_amdgcn_s_barrier();
        __builtin_amdgcn_sched_barrier(0);
        if (tk + 2 < nt) issue(tk + 2, (tk + 2) % 3);
        const int cb = tk % 3;
        bf16x8 af[4], bf[4];
#pragma unroll
        for (int ai = 0; ai < 4; ++ai)
            af[ai] = *(const bf16x8*)&As[cb][(wr * 64 + ai * 16 + lc) * 32 + lr * 8];
#pragma unroll
        for (int bj = 0; bj < 4; ++bj)
            bf[bj] = *(const bf16x8*)&Bs[cb][(wc * 64 + bj * 16 + lc) * 32 + lr * 8];
#pragma unroll
        for (int ai = 0; ai < 4; ++ai)
#pragma unroll
            for (int bj = 0; bj < 4; ++bj)
                acc[ai][bj] = __builtin_amdgcn_mfma_f32_16x16x32_bf16(af[ai], bf[bj],
                                                                      acc[ai][bj], 0, 0, 0);
    }

#pragma unroll
    for (int ai = 0; ai < 4; ++ai) {
#pragma unroll
        for (int bj = 0; bj < 4; ++bj) {
            int col  = bn + wc * 64 + bj * 16 + lc;
            float bs = bias[col];
            if (EPI == 3 && col >= 1536) {
                int row0 = bm + wr * 64 + ai * 16 + lr * 4;
                int bb   = row0 >> 10, key0 = row0 & 1023;
                int c    = col - 1536;
                int h    = c >> 6, d = c & 63;
                ushort4 pk;
                pk.x = f2bf(acc[ai][bj][0] + bs);
                pk.y = f2bf(acc[ai][bj][1] + bs);
                pk.z = f2bf(acc[ai][bj][2] + bs);
                pk.w = f2bf(acc[ai][bj][3] + bs);
                *(ushort4*)((ushort*)out2 +
                            ((size_t)(bb * 12 + h) * 64 + d) * 1024 + key0) = pk;
                continue;
            }
            const float qsc = (EPI == 3 && col < 768) ? 0.125f : 1.0f;
#pragma unroll
            for (int j = 0; j < 4; ++j) {
                int row   = bm + wr * 64 + ai * 16 + lr * 4 + j;
                size_t idx = (size_t)row * N + col;
                float val = acc[ai][bj][j] + bs;
                if (EPI == 4) {
                    val += ((const float*)resid)[idx];
                    ((ushort*)out)[idx] = f2bf(val);
                } else if (EPI == 5) {
                    val += bf2f(((const ushort*)resid)[idx]);
                    ((float*)out)[idx] = val;
                } else if (EPI == 2) {
                    val = 0.5f * val * (1.0f + erff(val * 0.70710678118f));
                    ((ushort*)out)[idx] = f2bf(val);
                } else {
                    ((ushort*)out)[idx] = f2bf(val * qsc);
                }
            }
        }
    }
}

// ------- attention: 32x32x16 MFMA, swapped QK^T, max-free softmax -------------
// qkv: bf16 [8192, 2304] (Q cols 0..767 pre-scaled by 1/8, K cols 768..1535)
// vT : bf16 [96][64][1024]   out: bf16 [8192, 768]
__global__ __launch_bounds__(256) void attn_mfma(const ushort* __restrict__ qkv,
                                                 const ushort* __restrict__ vT,
                                                 ushort* __restrict__ outb) {
    __shared__ ushort Kls[64 * 72];
    __shared__ ushort Vtls[64 * 72];

    const int bid = blockIdx.x;
    const int b   = bid / 96;
    const int rem = bid % 96;
    const int h   = rem >> 3;
    const int qc  = rem & 7;
    const int t    = threadIdx.x;
    const int w    = t >> 6;
    const int lane = t & 63;
    const int l31  = lane & 31;
    const int hi   = lane >> 5;
    const int q0   = qc * 128 + w * 32;
    const size_t bbase = (size_t)b * 1024;
    const ushort* vTh = vT + ((size_t)(b * 12 + h) * 64) * 1024;

    bf16x8 qb[4];
    {
        const size_t qrow = (bbase + q0 + l31) * 2304 + h * 64;
#pragma unroll
        for (int dblk = 0; dblk < 4; ++dblk)
            qb[dblk] = *(const bf16x8*)(qkv + qrow + dblk * 16 + hi * 8);
    }

    f32x16 O[2];
#pragma unroll
    for (int ob = 0; ob < 2; ++ob)
#pragma unroll
        for (int r = 0; r < 16; ++r) O[ob][r] = 0.0f;
    float l = 0.0f;

    for (int kt = 0; kt < 16; ++kt) {
        const int k0 = kt * 64;
        __syncthreads();
#pragma unroll
        for (int i = 0; i < 2; ++i) {
            int idx = t + i * 256;
            int key = idx >> 3, seg = idx & 7;
            uint4 u = *(const uint4*)(qkv + (bbase + k0 + key) * 2304 + 768 +
                                      h * 64 + seg * 8);
            *(uint4*)&Kls[key * 72 + seg * 8] = u;
        }
#pragma unroll
        for (int i = 0; i < 2; ++i) {
            int idx = t + i * 256;
            int d = idx >> 3, seg = idx & 7;
            uint4 u = *(const uint4*)(vTh + (size_t)d * 1024 + k0 + seg * 8);
            *(uint4*)&Vtls[d * 72 + seg * 8] = u;
        }
        __syncthreads();

        f32x16 s[2];
#pragma unroll
        for (int kb = 0; kb < 2; ++kb) {
            f32x16 acc;
#pragma unroll
            for (int r = 0; r < 16; ++r) acc[r] = 0.0f;
#pragma unroll
            for (int dblk = 0; dblk < 4; ++dblk) {
                bf16x8 ka = *(const bf16x8*)&Kls[(kb * 32 + l31) * 72 + dblk * 16 + hi * 8];
                acc = __builtin_amdgcn_mfma_f32_32x32x16_bf16(ka, qb[dblk], acc, 0, 0, 0);
            }
            s[kb] = acc;
        }

        float psum = 0.0f;
#pragma unroll
        for (int kb = 0; kb < 2; ++kb)
#pragma unroll
            for (int r = 0; r < 16; ++r) {
                float p = __expf(s[kb][r]);
                s[kb][r] = p;
                psum += p;
            }
        psum += __shfl_xor(psum, 32);
        l += psum;

        bf16x8 pb[4];
#pragma unroll
        for (int kb16 = 0; kb16 < 4; ++kb16) {
            const int sb = kb16 >> 1, r0 = (kb16 & 1) * 8;
            uint own01 = (uint)f2bf(s[sb][r0 + 0]) | ((uint)f2bf(s[sb][r0 + 1]) << 16);
            uint own23 = (uint)f2bf(s[sb][r0 + 2]) | ((uint)f2bf(s[sb][r0 + 3]) << 16);
            uint own45 = (uint)f2bf(s[sb][r0 + 4]) | ((uint)f2bf(s[sb][r0 + 5]) << 16);
            uint own67 = (uint)f2bf(s[sb][r0 + 6]) | ((uint)f2bf(s[sb][r0 + 7]) << 16);
            uint sw01 = __shfl_xor(own01, 32);
            uint sw23 = __shfl_xor(own23, 32);
            uint sw45 = __shfl_xor(own45, 32);
            uint sw67 = __shfl_xor(own67, 32);
            uint d0 = hi ? sw45 : own01;
            uint d1 = hi ? sw67 : own23;
            uint d2 = hi ? own45 : sw01;
            uint d3 = hi ? own67 : sw23;
            union { uint u[4]; bf16x8 v; } cvt;
            cvt.u[0] = d0; cvt.u[1] = d1; cvt.u[2] = d2; cvt.u[3] = d3;
            pb[kb16] = cvt.v;
        }

#pragma unroll
        for (int ob = 0; ob < 2; ++ob)
#pragma unroll
            for (int kb16 = 0; kb16 < 4; ++kb16) {
                bf16x8 va = *(const bf16x8*)&Vtls[(ob * 32 + l31) * 72 + kb16 * 16 + hi * 8];
                O[ob] = __builtin_amdgcn_mfma_f32_32x32x16_bf16(va, pb[kb16], O[ob], 0, 0, 0);
            }
    }

    const float inv = 1.0f / l;
    ushort* orow = outb + (bbase + q0 + l31) * 768 + h * 64;
#pragma unroll
    for (int ob = 0; ob < 2; ++ob)
#pragma unroll
        for (int qd = 0; qd < 4; ++qd) {
            ushort4 pk;
            pk.x = f2bf(O[ob][qd * 4 + 0] * inv);
            pk.y = f2bf(O[ob][qd * 4 + 1] * inv);
            pk.z = f2bf(O[ob][qd * 4 + 2] * inv);
            pk.w = f2bf(O[ob][qd * 4 + 3] * inv);
            *(ushort4*)(orow + ob * 32 + qd * 8 + hi * 4) = pk;
        }
}

// ---------------- launch ----------------
extern "C" void kernel_launch(void* const* d_in, const int* in_sizes, int n_in,
                              void* d_out, int out_size, void* d_ws, size_t ws_size,
                              hipStream_t stream) {
    const float* x      = (const float*)d_in[0];
    const float* ln1_g  = (const float*)d_in[1];
    const float* ln1_b  = (const float*)d_in[2];
    const float* qkv_w  = (const float*)d_in[3];
    const float* qkv_b  = (const float*)d_in[4];
    const float* proj_w = (const float*)d_in[5];
    const float* proj_b = (const float*)d_in[6];
    const float* ln2_g  = (const float*)d_in[7];
    const float* ln2_b  = (const float*)d_in[8];
    const float* fc1_w  = (const float*)d_in[9];
    const float* fc1_b  = (const float*)d_in[10];
    const float* fc2_w  = (const float*)d_in[11];
    const float* fc2_b  = (const float*)d_in[12];

    char* ws = (char*)d_ws;
    auto alloc = [&](size_t bytes) {
        char* p = ws;
        ws += (bytes + 255) & ~(size_t)255;
        return p;
    };
    ushort* qkv_wt  = (ushort*)alloc((size_t)768 * 2304 * 2);
    ushort* proj_wt = (ushort*)alloc((size_t)768 * 768 * 2);
    ushort* fc1_wt  = (ushort*)alloc((size_t)768 * 3072 * 2);
    ushort* fc2_wt  = (ushort*)alloc((size_t)3072 * 768 * 2);
    ushort* hb      = (ushort*)alloc((size_t)8192 * 768 * 2);
    ushort* qkvb    = (ushort*)alloc((size_t)8192 * 2304 * 2);
    ushort* vTb     = (ushort*)alloc((size_t)96 * 64 * 1024 * 2);
    ushort* ob      = (ushort*)alloc((size_t)8192 * 768 * 2);
    ushort* x1b     = (ushort*)alloc((size_t)8192 * 768 * 2);   // bf16 residual stream
    ushort* h2b     = (ushort*)alloc((size_t)8192 * 768 * 2);
    ushort* h3b     = (ushort*)alloc((size_t)8192 * 3072 * 2);

    // fused: 4 weight transposes + LN1 in one launch
    prep<<<15104, 256, 0, stream>>>(qkv_w, proj_w, fc1_w, fc2_w,
                                    qkv_wt, proj_wt, fc1_wt, fc2_wt,
                                    x, ln1_g, ln1_b, hb);
    gemm_bt<3, 1><<<18 * 64, 256, 0, stream>>>(
        hb, qkv_wt, qkv_b, nullptr, qkvb, vTb, 8192, 2304, 768, 18);
    attn_mfma<<<768, 256, 0, stream>>>(qkvb, vTb, ob);
    gemm_bt<4, 1><<<6 * 64, 256, 0, stream>>>(
        ob, proj_wt, proj_b, x, x1b, nullptr, 8192, 768, 768, 6);
    ln_bf16_bin<<<8192, 256, 0, stream>>>(x1b, ln2_g, ln2_b, h2b);
    gemm_bt<2, 1><<<24 * 64, 256, 0, stream>>>(
        h2b, fc1_wt, fc1_b, nullptr, h3b, nullptr, 8192, 3072, 768, 24);
    gemm_bt<5, 1><<<6 * 64, 256, 0, stream>>>(
        h3b, fc2_wt, fc2_b, x1b, (float*)d_out, nullptr, 8192, 768, 3072, 6);
}

// Round 25
// 282.880 us; speedup vs baseline: 1.0108x; 1.0104x over previous
//
#include <hip/hip_runtime.h>
#include <hip/hip_bf16.h>
#include <cstdint>

using f32x4   = __attribute__((ext_vector_type(4))) float;
using f32x16  = __attribute__((ext_vector_type(16))) float;
using bf16x8  = __attribute__((ext_vector_type(8))) short;

__device__ inline ushort f2bf(float f) {
    union { float f; uint u; } x; x.f = f;
    uint u = x.u;
    return (ushort)((u + 0x7FFFu + ((u >> 16) & 1u)) >> 16);
}

__device__ inline float bf2f(ushort v) {
    union { uint u; float f; } x; x.u = (uint)v << 16;
    return x.f;
}

// async global->LDS, 16B per lane; lds base must be wave-uniform
__device__ inline void gload16(const ushort* g, ushort* lds) {
    __builtin_amdgcn_global_load_lds(
        (const __attribute__((address_space(1))) unsigned int*)g,
        (__attribute__((address_space(3))) unsigned int*)lds, 16, 0, 0);
}

// ---------------- prep: 4 weight transposes + LN1, one launch ----------------
__device__ inline void transpose_body(const float* __restrict__ w,
                                      ushort* __restrict__ wt,
                                      int K, int N, int bx, int by,
                                      float (*tile)[33]) {
    const int bn = bx * 32, bk = by * 32;
    const int tx = threadIdx.x & 31, ty = threadIdx.x >> 5;
#pragma unroll
    for (int i = 0; i < 32; i += 8)
        tile[ty + i][tx] = w[(size_t)(bk + ty + i) * N + bn + tx];
    __syncthreads();
#pragma unroll
    for (int i = 0; i < 32; i += 8)
        wt[(size_t)(bn + ty + i) * K + bk + tx] = f2bf(tile[tx][ty + i]);
}

__device__ inline void ln_body(const float* __restrict__ x,
                               const float* __restrict__ g,
                               const float* __restrict__ b,
                               ushort* __restrict__ out, int row,
                               float* sa, float* sb) {
    const float* xr = x + (size_t)row * 768;
    const int t = threadIdx.x;
    float v0 = xr[t], v1 = xr[t + 256], v2 = xr[t + 512];
    float s  = v0 + v1 + v2;
    float sq = v0 * v0 + v1 * v1 + v2 * v2;
#pragma unroll
    for (int off = 32; off > 0; off >>= 1) {
        s  += __shfl_down(s, off);
        sq += __shfl_down(sq, off);
    }
    const int wv = t >> 6, lane = t & 63;
    if (lane == 0) { sa[wv] = s; sb[wv] = sq; }
    __syncthreads();
    s  = sa[0] + sa[1] + sa[2] + sa[3];
    sq = sb[0] + sb[1] + sb[2] + sb[3];
    const float mu   = s * (1.0f / 768.0f);
    const float var  = sq * (1.0f / 768.0f) - mu * mu;
    const float rstd = rsqrtf(var + 1e-5f);
    ushort* orow = out + (size_t)row * 768;
    orow[t]       = f2bf((v0 - mu) * rstd * g[t]       + b[t]);
    orow[t + 256] = f2bf((v1 - mu) * rstd * g[t + 256] + b[t + 256]);
    orow[t + 512] = f2bf((v2 - mu) * rstd * g[t + 512] + b[t + 512]);
}

__global__ __launch_bounds__(256) void prep(const float* __restrict__ qkv_w,
                                            const float* __restrict__ proj_w,
                                            const float* __restrict__ fc1_w,
                                            const float* __restrict__ fc2_w,
                                            ushort* __restrict__ qkv_wt,
                                            ushort* __restrict__ proj_wt,
                                            ushort* __restrict__ fc1_wt,
                                            ushort* __restrict__ fc2_wt,
                                            const float* __restrict__ x,
                                            const float* __restrict__ ln1_g,
                                            const float* __restrict__ ln1_b,
                                            ushort* __restrict__ hb) {
    __shared__ float tile[32][33];
    __shared__ float sa[4], sb[4];
    int blk = blockIdx.x;
    if (blk < 1728)      transpose_body(qkv_w, qkv_wt, 768, 2304, blk % 72, blk / 72, tile);
    else if (blk < 2304) { blk -= 1728; transpose_body(proj_w, proj_wt, 768, 768,  blk % 24, blk / 24, tile); }
    else if (blk < 4608) { blk -= 2304; transpose_body(fc1_w,  fc1_wt,  768, 3072, blk % 96, blk / 96, tile); }
    else if (blk < 6912) { blk -= 4608; transpose_body(fc2_w,  fc2_wt,  3072, 768, blk % 24, blk / 24, tile); }
    else                 ln_body(x, ln1_g, ln1_b, hb, blk - 6912, sa, sb);
}

// ---------------- LayerNorm, bf16 input variant (for ln2 over bf16 x1) --------
__global__ __launch_bounds__(256) void ln_bf16_bin(const ushort* __restrict__ x,
                                                   const float* __restrict__ g,
                                                   const float* __restrict__ b,
                                                   ushort* __restrict__ out) {
    __shared__ float sa[4], sb[4];
    const int row = blockIdx.x;
    const ushort* xr = x + (size_t)row * 768;
    const int t = threadIdx.x;
    float v0 = bf2f(xr[t]), v1 = bf2f(xr[t + 256]), v2 = bf2f(xr[t + 512]);
    float s  = v0 + v1 + v2;
    float sq = v0 * v0 + v1 * v1 + v2 * v2;
#pragma unroll
    for (int off = 32; off > 0; off >>= 1) {
        s  += __shfl_down(s, off);
        sq += __shfl_down(sq, off);
    }
    const int wv = t >> 6, lane = t & 63;
    if (lane == 0) { sa[wv] = s; sb[wv] = sq; }
    __syncthreads();
    s  = sa[0] + sa[1] + sa[2] + sa[3];
    sq = sb[0] + sb[1] + sb[2] + sb[3];
    const float mu   = s * (1.0f / 768.0f);
    const float var  = sq * (1.0f / 768.0f) - mu * mu;
    const float rstd = rsqrtf(var + 1e-5f);
    ushort* orow = out + (size_t)row * 768;
    orow[t]       = f2bf((v0 - mu) * rstd * g[t]       + b[t]);
    orow[t + 256] = f2bf((v1 - mu) * rstd * g[t + 256] + b[t + 256]);
    orow[t + 512] = f2bf((v2 - mu) * rstd * g[t + 512] + b[t + 512]);
}

// ---- bf16 MFMA GEMM: BK=32, TRIPLE-buffered LDS, 2-deep prefetch (best) ------
// EPI: 0 = bias -> bf16; 2 = bias + gelu -> bf16
// EPI: 3 = qkv mode: cols < 768 (Q) -> bf16 * 1/8; 768..1535 (K) -> bf16;
//          >= 1536 (V) -> transposed store into out2 as vT[(b*12+h)*64+d][key]
// EPI: 4 = bias + f32 residual -> bf16 out (proj)
// EPI: 5 = bias + bf16 residual -> f32 out (fc2)
// SWZ: 1 = row-grouping XCD swizzle; requires (M/128) % 8 == 0.
template <int EPI, int SWZ>
__global__ __launch_bounds__(256) void gemm_bt(const ushort* __restrict__ A,
                                               const ushort* __restrict__ Bt,
                                               const float* __restrict__ bias,
                                               const void* __restrict__ resid,
                                               void* __restrict__ out,
                                               void* __restrict__ out2,
                                               int M, int N, int K, int gx) {
    __shared__ ushort As[3][128 * 32];
    __shared__ ushort Bs[3][128 * 32];
    int bm, bn;
    if (SWZ) {
        const int bid = blockIdx.x;
        const int x = bid & 7, s = bid >> 3;
        bm = ((s / gx) * 8 + x) * 128;
        bn = (s % gx) * 128;
    } else {
        bm = blockIdx.y * 128;
        bn = blockIdx.x * 128;
    }
    const int t    = threadIdx.x;
    const int lane = t & 63;
    const int w    = t >> 6;
    const int wr   = w >> 1, wc = w & 1;
    const int lr   = lane >> 4, lc = lane & 15;

    const f32x4 fzero = {0.f, 0.f, 0.f, 0.f};
    f32x4 acc[4][4];
#pragma unroll
    for (int ai = 0; ai < 4; ++ai)
#pragma unroll
        for (int bj = 0; bj < 4; ++bj) acc[ai][bj] = fzero;

    const int srow = lane >> 2;
    const int sk8  = (lane & 3) * 8;
    const ushort* Ag0 = A  + (size_t)(bm + w * 16 + srow) * K + sk8;
    const ushort* Ag1 = Ag0 + (size_t)64 * K;
    const ushort* Bg0 = Bt + (size_t)(bn + w * 16 + srow) * K + sk8;
    const ushort* Bg1 = Bg0 + (size_t)64 * K;
    const int lo0 = (w * 16) * 32, lo1 = (64 + w * 16) * 32;

    const int nt = K >> 5;
    auto issue = [&](int tile, int buf) {
        const int kb = tile << 5;
        gload16(Ag0 + kb, &As[buf][lo0]);
        gload16(Ag1 + kb, &As[buf][lo1]);
        gload16(Bg0 + kb, &Bs[buf][lo0]);
        gload16(Bg1 + kb, &Bs[buf][lo1]);
    };
    issue(0, 0);
    if (nt > 1) issue(1, 1);

    for (int tk = 0; tk < nt; ++tk) {
        if (tk + 1 < nt) asm volatile("s_waitcnt vmcnt(4)" ::: "memory");
        else             asm volatile("s_waitcnt vmcnt(0)" ::: "memory");
        __builtin_amdgcn_sched_barrier(0);
        __builtin_amdgcn_s_barrier();
        __builtin_amdgcn_sched_barrier(0);
        if (tk + 2 < nt) issue(tk + 2, (tk + 2) % 3);
        const int cb = tk % 3;
        bf16x8 af[4], bf[4];
#pragma unroll
        for (int ai = 0; ai < 4; ++ai)
            af[ai] = *(const bf16x8*)&As[cb][(wr * 64 + ai * 16 + lc) * 32 + lr * 8];
#pragma unroll
        for (int bj = 0; bj < 4; ++bj)
            bf[bj] = *(const bf16x8*)&Bs[cb][(wc * 64 + bj * 16 + lc) * 32 + lr * 8];
#pragma unroll
        for (int ai = 0; ai < 4; ++ai)
#pragma unroll
            for (int bj = 0; bj < 4; ++bj)
                acc[ai][bj] = __builtin_amdgcn_mfma_f32_16x16x32_bf16(af[ai], bf[bj],
                                                                      acc[ai][bj], 0, 0, 0);
    }

#pragma unroll
    for (int ai = 0; ai < 4; ++ai) {
#pragma unroll
        for (int bj = 0; bj < 4; ++bj) {
            int col  = bn + wc * 64 + bj * 16 + lc;
            float bs = bias[col];
            if (EPI == 3 && col >= 1536) {
                int row0 = bm + wr * 64 + ai * 16 + lr * 4;
                int bb   = row0 >> 10, key0 = row0 & 1023;
                int c    = col - 1536;
                int h    = c >> 6, d = c & 63;
                ushort4 pk;
                pk.x = f2bf(acc[ai][bj][0] + bs);
                pk.y = f2bf(acc[ai][bj][1] + bs);
                pk.z = f2bf(acc[ai][bj][2] + bs);
                pk.w = f2bf(acc[ai][bj][3] + bs);
                *(ushort4*)((ushort*)out2 +
                            ((size_t)(bb * 12 + h) * 64 + d) * 1024 + key0) = pk;
                continue;
            }
            const float qsc = (EPI == 3 && col < 768) ? 0.125f : 1.0f;
#pragma unroll
            for (int j = 0; j < 4; ++j) {
                int row   = bm + wr * 64 + ai * 16 + lr * 4 + j;
                size_t idx = (size_t)row * N + col;
                float val = acc[ai][bj][j] + bs;
                if (EPI == 4) {
                    val += ((const float*)resid)[idx];
                    ((ushort*)out)[idx] = f2bf(val);
                } else if (EPI == 5) {
                    val += bf2f(((const ushort*)resid)[idx]);
                    ((float*)out)[idx] = val;
                } else if (EPI == 2) {
                    val = 0.5f * val * (1.0f + erff(val * 0.70710678118f));
                    ((ushort*)out)[idx] = f2bf(val);
                } else {
                    ((ushort*)out)[idx] = f2bf(val * qsc);
                }
            }
        }
    }
}

// ------- attention: 32x32x16 MFMA, swapped QK^T, max-free softmax -------------
// NEW (R25): XCD-locality remap. Default dispatch round-robins bid across
// XCDs (bid&7 = XCD). tile = (bid&7)*96 + (bid>>3) puts all 96 blocks of one
// batch (12 heads x 8 q-chunks) on ONE XCD: its K+V^T working set is
// 12 x 256KB = 3MB < 4MB L2, so the 8-fold q-chunk panel re-reads become L2
// hits (FETCH ~104MB -> ~55MB). Bijective for grid 768 = 8*96.
// qkv: bf16 [8192, 2304] (Q cols 0..767 pre-scaled by 1/8, K cols 768..1535)
// vT : bf16 [96][64][1024]   out: bf16 [8192, 768]
__global__ __launch_bounds__(256) void attn_mfma(const ushort* __restrict__ qkv,
                                                 const ushort* __restrict__ vT,
                                                 ushort* __restrict__ outb) {
    __shared__ ushort Kls[64 * 72];
    __shared__ ushort Vtls[64 * 72];

    const int bid  = blockIdx.x;
    const int tile = (bid & 7) * 96 + (bid >> 3);   // XCD-local batch mapping
    const int b   = tile / 96;
    const int rem = tile % 96;
    const int h   = rem >> 3;
    const int qc  = rem & 7;
    const int t    = threadIdx.x;
    const int w    = t >> 6;
    const int lane = t & 63;
    const int l31  = lane & 31;
    const int hi   = lane >> 5;
    const int q0   = qc * 128 + w * 32;
    const size_t bbase = (size_t)b * 1024;
    const ushort* vTh = vT + ((size_t)(b * 12 + h) * 64) * 1024;

    bf16x8 qb[4];
    {
        const size_t qrow = (bbase + q0 + l31) * 2304 + h * 64;
#pragma unroll
        for (int dblk = 0; dblk < 4; ++dblk)
            qb[dblk] = *(const bf16x8*)(qkv + qrow + dblk * 16 + hi * 8);
    }

    f32x16 O[2];
#pragma unroll
    for (int ob = 0; ob < 2; ++ob)
#pragma unroll
        for (int r = 0; r < 16; ++r) O[ob][r] = 0.0f;
    float l = 0.0f;

    for (int kt = 0; kt < 16; ++kt) {
        const int k0 = kt * 64;
        __syncthreads();
#pragma unroll
        for (int i = 0; i < 2; ++i) {
            int idx = t + i * 256;
            int key = idx >> 3, seg = idx & 7;
            uint4 u = *(const uint4*)(qkv + (bbase + k0 + key) * 2304 + 768 +
                                      h * 64 + seg * 8);
            *(uint4*)&Kls[key * 72 + seg * 8] = u;
        }
#pragma unroll
        for (int i = 0; i < 2; ++i) {
            int idx = t + i * 256;
            int d = idx >> 3, seg = idx & 7;
            uint4 u = *(const uint4*)(vTh + (size_t)d * 1024 + k0 + seg * 8);
            *(uint4*)&Vtls[d * 72 + seg * 8] = u;
        }
        __syncthreads();

        f32x16 s[2];
#pragma unroll
        for (int kb = 0; kb < 2; ++kb) {
            f32x16 acc;
#pragma unroll
            for (int r = 0; r < 16; ++r) acc[r] = 0.0f;
#pragma unroll
            for (int dblk = 0; dblk < 4; ++dblk) {
                bf16x8 ka = *(const bf16x8*)&Kls[(kb * 32 + l31) * 72 + dblk * 16 + hi * 8];
                acc = __builtin_amdgcn_mfma_f32_32x32x16_bf16(ka, qb[dblk], acc, 0, 0, 0);
            }
            s[kb] = acc;
        }

        float psum = 0.0f;
#pragma unroll
        for (int kb = 0; kb < 2; ++kb)
#pragma unroll
            for (int r = 0; r < 16; ++r) {
                float p = __expf(s[kb][r]);
                s[kb][r] = p;
                psum += p;
            }
        psum += __shfl_xor(psum, 32);
        l += psum;

        bf16x8 pb[4];
#pragma unroll
        for (int kb16 = 0; kb16 < 4; ++kb16) {
            const int sb = kb16 >> 1, r0 = (kb16 & 1) * 8;
            uint own01 = (uint)f2bf(s[sb][r0 + 0]) | ((uint)f2bf(s[sb][r0 + 1]) << 16);
            uint own23 = (uint)f2bf(s[sb][r0 + 2]) | ((uint)f2bf(s[sb][r0 + 3]) << 16);
            uint own45 = (uint)f2bf(s[sb][r0 + 4]) | ((uint)f2bf(s[sb][r0 + 5]) << 16);
            uint own67 = (uint)f2bf(s[sb][r0 + 6]) | ((uint)f2bf(s[sb][r0 + 7]) << 16);
            uint sw01 = __shfl_xor(own01, 32);
            uint sw23 = __shfl_xor(own23, 32);
            uint sw45 = __shfl_xor(own45, 32);
            uint sw67 = __shfl_xor(own67, 32);
            uint d0 = hi ? sw45 : own01;
            uint d1 = hi ? sw67 : own23;
            uint d2 = hi ? own45 : sw01;
            uint d3 = hi ? own67 : sw23;
            union { uint u[4]; bf16x8 v; } cvt;
            cvt.u[0] = d0; cvt.u[1] = d1; cvt.u[2] = d2; cvt.u[3] = d3;
            pb[kb16] = cvt.v;
        }

#pragma unroll
        for (int ob = 0; ob < 2; ++ob)
#pragma unroll
            for (int kb16 = 0; kb16 < 4; ++kb16) {
                bf16x8 va = *(const bf16x8*)&Vtls[(ob * 32 + l31) * 72 + kb16 * 16 + hi * 8];
                O[ob] = __builtin_amdgcn_mfma_f32_32x32x16_bf16(va, pb[kb16], O[ob], 0, 0, 0);
            }
    }

    const float inv = 1.0f / l;
    ushort* orow = outb + (bbase + q0 + l31) * 768 + h * 64;
#pragma unroll
    for (int ob = 0; ob < 2; ++ob)
#pragma unroll
        for (int qd = 0; qd < 4; ++qd) {
            ushort4 pk;
            pk.x = f2bf(O[ob][qd * 4 + 0] * inv);
            pk.y = f2bf(O[ob][qd * 4 + 1] * inv);
            pk.z = f2bf(O[ob][qd * 4 + 2] * inv);
            pk.w = f2bf(O[ob][qd * 4 + 3] * inv);
            *(ushort4*)(orow + ob * 32 + qd * 8 + hi * 4) = pk;
        }
}

// ---------------- launch ----------------
extern "C" void kernel_launch(void* const* d_in, const int* in_sizes, int n_in,
                              void* d_out, int out_size, void* d_ws, size_t ws_size,
                              hipStream_t stream) {
    const float* x      = (const float*)d_in[0];
    const float* ln1_g  = (const float*)d_in[1];
    const float* ln1_b  = (const float*)d_in[2];
    const float* qkv_w  = (const float*)d_in[3];
    const float* qkv_b  = (const float*)d_in[4];
    const float* proj_w = (const float*)d_in[5];
    const float* proj_b = (const float*)d_in[6];
    const float* ln2_g  = (const float*)d_in[7];
    const float* ln2_b  = (const float*)d_in[8];
    const float* fc1_w  = (const float*)d_in[9];
    const float* fc1_b  = (const float*)d_in[10];
    const float* fc2_w  = (const float*)d_in[11];
    const float* fc2_b  = (const float*)d_in[12];

    char* ws = (char*)d_ws;
    auto alloc = [&](size_t bytes) {
        char* p = ws;
        ws += (bytes + 255) & ~(size_t)255;
        return p;
    };
    ushort* qkv_wt  = (ushort*)alloc((size_t)768 * 2304 * 2);
    ushort* proj_wt = (ushort*)alloc((size_t)768 * 768 * 2);
    ushort* fc1_wt  = (ushort*)alloc((size_t)768 * 3072 * 2);
    ushort* fc2_wt  = (ushort*)alloc((size_t)3072 * 768 * 2);
    ushort* hb      = (ushort*)alloc((size_t)8192 * 768 * 2);
    ushort* qkvb    = (ushort*)alloc((size_t)8192 * 2304 * 2);
    ushort* vTb     = (ushort*)alloc((size_t)96 * 64 * 1024 * 2);
    ushort* ob      = (ushort*)alloc((size_t)8192 * 768 * 2);
    ushort* x1b     = (ushort*)alloc((size_t)8192 * 768 * 2);   // bf16 residual stream
    ushort* h2b     = (ushort*)alloc((size_t)8192 * 768 * 2);
    ushort* h3b     = (ushort*)alloc((size_t)8192 * 3072 * 2);

    // fused: 4 weight transposes + LN1 in one launch
    prep<<<15104, 256, 0, stream>>>(qkv_w, proj_w, fc1_w, fc2_w,
                                    qkv_wt, proj_wt, fc1_wt, fc2_wt,
                                    x, ln1_g, ln1_b, hb);
    gemm_bt<3, 1><<<18 * 64, 256, 0, stream>>>(
        hb, qkv_wt, qkv_b, nullptr, qkvb, vTb, 8192, 2304, 768, 18);
    attn_mfma<<<768, 256, 0, stream>>>(qkvb, vTb, ob);
    gemm_bt<4, 1><<<6 * 64, 256, 0, stream>>>(
        ob, proj_wt, proj_b, x, x1b, nullptr, 8192, 768, 768, 6);
    ln_bf16_bin<<<8192, 256, 0, stream>>>(x1b, ln2_g, ln2_b, h2b);
    gemm_bt<2, 1><<<24 * 64, 256, 0, stream>>>(
        h2b, fc1_wt, fc1_b, nullptr, h3b, nullptr, 8192, 3072, 768, 24);
    gemm_bt<5, 1><<<6 * 64, 256, 0, stream>>>(
        h3b, fc2_wt, fc2_b, x1b, (float*)d_out, nullptr, 8192, 768, 3072, 6);
}